// Round 3
// baseline (381.560 us; speedup 1.0000x reference)
//
#include <hip/hip_runtime.h>

#define BATCH 32
#define NRr 32
#define NFf 128
#define NHh 64
#define NFHh 64
#define TI 2

__device__ __forceinline__ float dot4(float4 a, float4 b) {
    return fmaf(a.x, b.x, fmaf(a.y, b.y, fmaf(a.z, b.z, a.w * b.w)));
}

// ---------------------------------------------------------------------------
// intra: x -> x + nmlp([x, softmax(qk^T) v])  for all 4 tensors in one launch.
// rh/fh blocks additionally emit the y-side precompute (w, yv) for stages 5/6.
// grid = 288 blocks: robot [0,32), frontier [32,160), rh [160,224), fh [224,288)
// ---------------------------------------------------------------------------
__global__ __launch_bounds__(256) void intra_kernel(
    const float* __restrict__ robot, const float* __restrict__ frontier,
    const float* __restrict__ rhist, const float* __restrict__ fhist,
    const float* __restrict__ Wq, const float* __restrict__ bq,
    const float* __restrict__ Wk, const float* __restrict__ bk,
    const float* __restrict__ Wv, const float* __restrict__ bv,
    const float* __restrict__ Wn1, const float* __restrict__ bn1,
    const float* __restrict__ Wn2, const float* __restrict__ bn2,
    const float* __restrict__ We1,
    float* __restrict__ o_robot, float* __restrict__ o_frontier,
    float* __restrict__ o_rh, float* __restrict__ o_fh,
    float* __restrict__ w5, float* __restrict__ yv5,
    float* __restrict__ w6, float* __restrict__ yv6)
{
    __shared__ __align__(16) float sXc[1024];    // chunk rows of x (32x32)
    __shared__ __align__(16) float sQ[1024];     // chunk q (32x32); later sOut
    __shared__ __align__(16) float sAgg[1024];   // chunk agg (32x32)
    __shared__ __align__(16) float sS[4096];     // scores chunk (32 x N)
    __shared__ __align__(16) float sKT[4128];    // K^T [32][129]; later yk [32][33]
    __shared__ __align__(16) float sVT[8192];    // V (N*32), later overlaid by T (32x256)

    const int blk = blockIdx.x, tid = threadIdx.x;
    const float* xin; float* xout; int N, lgN, b, chunk;
    float* wOut = nullptr; float* yvOut = nullptr;
    if (blk < 32)       { xin=robot;    xout=o_robot;    N=32;  lgN=5; b=blk;          chunk=0; }
    else if (blk < 160) { xin=frontier; xout=o_frontier; N=128; lgN=7; b=(blk-32)>>2;  chunk=(blk-32)&3; }
    else if (blk < 224) { xin=rhist;    xout=o_rh;       N=64;  lgN=6; b=(blk-160)>>1; chunk=(blk-160)&1; wOut=w5; yvOut=yv5; }
    else                { xin=fhist;    xout=o_fh;       N=64;  lgN=6; b=(blk-224)>>1; chunk=(blk-224)&1; wOut=w6; yvOut=yv6; }
    const bool isPre = (wOut != nullptr);

    const float* xb = xin + (size_t)b * N * 32;
    const int r0 = chunk << 5;
    const int d = tid & 31;

    // load chunk rows of x into LDS
    {
        int idx = tid;
        #pragma unroll
        for (int it = 0; it < 4; ++it, idx += 256)
            sXc[idx] = xb[(r0 << 5) + idx];
    }

    // K^T, V for all N rows; weight rows hoisted to registers
    {
        const float4* wk4 = (const float4*)(Wk + (d << 5));
        const float4* wv4 = (const float4*)(Wv + (d << 5));
        float4 wk[8], wv[8];
        #pragma unroll
        for (int k = 0; k < 8; ++k) { wk[k] = wk4[k]; wv[k] = wv4[k]; }
        const float bkd = bk[d], bvd = bv[d];
        for (int idx = tid; idx < (N << 5); idx += 256) {
            int j = idx >> 5;
            const float4* xr = (const float4*)(xb + (j << 5));
            float aK = bkd, aV = bvd;
            #pragma unroll
            for (int k = 0; k < 8; ++k) {
                float4 xv = xr[k];
                aK += dot4(wk[k], xv);
                aV += dot4(wv[k], xv);
            }
            sKT[d * 129 + j] = aK;
            sVT[(j << 5) + d] = aV;
        }
    }
    __syncthreads();

    // Q for chunk rows (weight row hoisted)
    {
        const float4* wq4 = (const float4*)(Wq + (d << 5));
        float4 wq[8];
        #pragma unroll
        for (int k = 0; k < 8; ++k) wq[k] = wq4[k];
        const float bqd = bq[d];
        int idx = tid;
        #pragma unroll
        for (int it = 0; it < 4; ++it, idx += 256) {
            int r = idx >> 5;
            const float4* xr = (const float4*)(sXc + (r << 5));
            float a = bqd;
            #pragma unroll
            for (int k = 0; k < 8; ++k) a += dot4(wq[k], xr[k]);
            sQ[idx] = a;
        }
    }
    __syncthreads();

    // scores chunk: [32, N]; K^T reads conflict-free, Q reads broadcast
    for (int idx = tid; idx < (N << 5); idx += 256) {
        int r = idx >> lgN, j = idx & (N - 1);
        const float* qr = sQ + (r << 5);
        float a = 0.f;
        #pragma unroll
        for (int e = 0; e < 32; ++e) a = fmaf(qr[e], sKT[e * 129 + j], a);
        sS[idx] = a;
    }
    __syncthreads();

    // softmax per row: 32 rows x 8 lanes
    {
        int r = tid >> 3, l = tid & 7;
        float* row = sS + (r << lgN);
        float m = -1e30f;
        for (int j = l; j < N; j += 8) m = fmaxf(m, row[j]);
        m = fmaxf(m, __shfl_xor(m, 4));
        m = fmaxf(m, __shfl_xor(m, 2));
        m = fmaxf(m, __shfl_xor(m, 1));
        float s = 0.f;
        for (int j = l; j < N; j += 8) { float ev = __expf(row[j] - m); row[j] = ev; s += ev; }
        s += __shfl_xor(s, 4); s += __shfl_xor(s, 2); s += __shfl_xor(s, 1);
        float inv = 1.0f / s;
        for (int j = l; j < N; j += 8) row[j] *= inv;
    }
    __syncthreads();

    // agg = e @ V
    {
        int idx = tid;
        #pragma unroll
        for (int it = 0; it < 4; ++it, idx += 256) {
            int r = idx >> 5;
            const float* er = sS + (r << lgN);
            float a = 0.f;
            for (int j = 0; j < N; ++j) a = fmaf(er[j], sVT[(j << 5) + d], a);
            sAgg[idx] = a;
        }
    }
    __syncthreads();

    // T = relu([x, agg] @ Wn1^T + bn1): thread h = tid, loop over 32 rows
    float* sT = sVT;
    {
        const float4* w14 = (const float4*)(Wn1 + (tid << 6));
        float4 w1r[16];
        #pragma unroll
        for (int k = 0; k < 16; ++k) w1r[k] = w14[k];
        const float b1 = bn1[tid];
        for (int r = 0; r < 32; ++r) {
            const float4* xr = (const float4*)(sXc + (r << 5));
            const float4* ar = (const float4*)(sAgg + (r << 5));
            float a = b1;
            #pragma unroll
            for (int k = 0; k < 8; ++k) a += dot4(w1r[k], xr[k]);
            #pragma unroll
            for (int k = 0; k < 8; ++k) a += dot4(w1r[8 + k], ar[k]);
            sT[(r << 8) + tid] = fmaxf(a, 0.f);
        }
    }
    __syncthreads();

    // out = x + T @ Wn2^T + bn2: thread (rg=tid>>5, d), 4 rows each, h chunked
    float* sOut = sQ;  // reuse
    {
        const int rg = tid >> 5;
        float acc[4] = {0.f, 0.f, 0.f, 0.f};
        #pragma unroll
        for (int hc = 0; hc < 4; ++hc) {
            const float4* w24 = (const float4*)(Wn2 + (d << 8) + (hc << 6));
            float4 w2r[16];
            #pragma unroll
            for (int k = 0; k < 16; ++k) w2r[k] = w24[k];
            #pragma unroll
            for (int p = 0; p < 4; ++p) {
                int r = rg + (p << 3);
                const float4* tr = (const float4*)(sT + (r << 8) + (hc << 6));
                float a = 0.f;
                #pragma unroll
                for (int k = 0; k < 16; ++k) a += dot4(w2r[k], tr[k]);
                acc[p] += a;
            }
        }
        const float b2 = bn2[d];
        #pragma unroll
        for (int p = 0; p < 4; ++p) {
            int r = rg + (p << 3);
            float v = sXc[(r << 5) + d] + b2 + acc[p];
            xout[((size_t)b * N << 5) + ((r0 + r) << 5) + d] = v;
            if (isPre) sOut[(r << 5) + d] = v;
        }
    }

    // fused pre_y for rh/fh: yk -> sYK, yv -> global, w rows -> global
    if (isPre) {
        __syncthreads();
        float* sYK = sKT;   // [32][33]
        {
            const float4* wk4 = (const float4*)(Wk + (d << 5));
            const float4* wv4 = (const float4*)(Wv + (d << 5));
            float4 wk[8], wv[8];
            #pragma unroll
            for (int k = 0; k < 8; ++k) { wk[k] = wk4[k]; wv[k] = wv4[k]; }
            const float bkd = bk[d], bvd = bv[d];
            const int rg = tid >> 5;
            #pragma unroll
            for (int p = 0; p < 4; ++p) {
                int r = rg + (p << 3);
                const float4* orow = (const float4*)(sOut + (r << 5));
                float aK = bkd, aV = bvd;
                #pragma unroll
                for (int k = 0; k < 8; ++k) { aK += dot4(wk[k], orow[k]); aV += dot4(wv[k], orow[k]); }
                sYK[r * 33 + d] = aK;
                yvOut[(((size_t)(b * N + r0 + r)) << 5) + d] = aV;
            }
        }
        __syncthreads();
        {
            const float* w1 = We1 + tid * 65 + 32;
            #pragma unroll
            for (int rc = 0; rc < 2; ++rc) {
                float acc[16];
                #pragma unroll
                for (int r2 = 0; r2 < 16; ++r2) acc[r2] = 0.f;
                #pragma unroll
                for (int e = 0; e < 32; ++e) {
                    float we = w1[e];
                    #pragma unroll
                    for (int r2 = 0; r2 < 16; ++r2)
                        acc[r2] = fmaf(we, sYK[(rc * 16 + r2) * 33 + e], acc[r2]);
                }
                #pragma unroll
                for (int r2 = 0; r2 < 16; ++r2)
                    wOut[(((size_t)(b * N + r0 + rc * 16 + r2)) << 8) + tid] = acc[r2];
            }
        }
    }
}

// ---------------------------------------------------------------------------
// inter v3: block = (b, tile of TI=2 i's). Phase-3 j-loop is register-resident
// (u/c/w2 hoisted) with float4 w-row loads. Stage-B blocks optionally emit the
// y-side precompute (wPre/yvPre) for the NEXT inter stage from their out rows.
// ---------------------------------------------------------------------------
__global__ __launch_bounds__(256) void inter_main_kernel(
    const float* __restrict__ xA, int NxA, const float* __restrict__ wA, const float* __restrict__ yvA,
    int NyA, const float* __restrict__ disA, float* __restrict__ outA, float* __restrict__ eA,
    float* __restrict__ wPreA, float* __restrict__ yvPreA, int nBlkA,
    const float* __restrict__ xB, int NxB, const float* __restrict__ wB, const float* __restrict__ yvB,
    int NyB, const float* __restrict__ disB, float* __restrict__ outB, float* __restrict__ eB,
    float* __restrict__ wPreB, float* __restrict__ yvPreB,
    const float* __restrict__ Wq, const float* __restrict__ bq,
    const float* __restrict__ Wk, const float* __restrict__ bk,
    const float* __restrict__ Wv, const float* __restrict__ bv,
    const float* __restrict__ We1, const float* __restrict__ be1,
    const float* __restrict__ We2,
    const float* __restrict__ Wn1, const float* __restrict__ bn1,
    const float* __restrict__ Wn2, const float* __restrict__ bn2)
{
    __shared__ __align__(16) float sX[64], sQ[64], sAgg[64], sOut[64];
    __shared__ __align__(16) float sYK[66];       // [2][33]
    __shared__ __align__(16) float sDis[256];     // [TI][128]
    __shared__ __align__(16) float sU[512];       // [TI][256]
    __shared__ __align__(16) float sC[256], sW2[256];
    __shared__ __align__(16) float sS[256];       // [TI][128]
    __shared__ __align__(16) float sRed[512];     // [8][TI*32]
    __shared__ __align__(16) float sT[512];       // [TI][256]

    const int blk = blockIdx.x, tid = threadIdx.x;
    const float* x; int Nx; const float* w; const float* yv; int Ny;
    const float* dis; float* outp; float* ep; float* wPre; float* yvPre; int idx;
    if (blk < nBlkA) { x=xA; Nx=NxA; w=wA; yv=yvA; Ny=NyA; dis=disA; outp=outA; ep=eA; wPre=wPreA; yvPre=yvPreA; idx=blk; }
    else             { x=xB; Nx=NxB; w=wB; yv=yvB; Ny=NyB; dis=disB; outp=outB; ep=eB; wPre=wPreB; yvPre=yvPreB; idx=blk-nBlkA; }
    const int tiles = Nx >> 1;
    const int b = idx / tiles, i0 = (idx - b * tiles) << 1;
    const float* xrow = x + ((size_t)(b * Nx + i0)) * 32;

    // phase 0: stage x tile + dis tile (float4)
    if (tid < 64) sX[tid] = xrow[tid];
    {
        int per = Ny >> 2;                 // float4s per row (16 or 32)
        if (tid < (per << 1)) {
            int il = (tid >= per) ? 1 : 0, jq = tid - il * per;
            ((float4*)sDis)[(il << 5) + jq] =
                ((const float4*)(dis + ((size_t)(b * Nx + i0 + il)) * Ny))[jq];
        }
    }
    __syncthreads();

    // phase 1: Q for TI rows
    if (tid < 64) {
        int il = tid >> 5, dd = tid & 31;
        const float4* wq4 = (const float4*)(Wq + (dd << 5));
        const float4* xr = (const float4*)(sX + (il << 5));
        float a = bq[dd];
        #pragma unroll
        for (int k = 0; k < 8; ++k) a += dot4(wq4[k], xr[k]);
        sQ[tid] = a;
    }
    __syncthreads();

    // phase 2: u, c, w2
    {
        const float* w1 = We1 + tid * 65;
        float a0 = be1[tid], a1 = a0;
        #pragma unroll
        for (int e = 0; e < 32; ++e) {
            float we = w1[e];
            a0 = fmaf(we, sQ[e], a0);
            a1 = fmaf(we, sQ[32 + e], a1);
        }
        sU[tid] = a0; sU[256 + tid] = a1;
        sC[tid] = w1[64];
        sW2[tid] = We2[tid];
    }
    __syncthreads();

    // phase 3: scores; lane hh owns h = hh*8..hh*8+7, all state in registers
    {
        const int jg = tid >> 5, hh = tid & 31;
        float ur0[8], ur1[8], cr[8], w2r[8];
        #pragma unroll
        for (int k = 0; k < 8; ++k) {
            int h = (hh << 3) + k;
            cr[k] = sC[h]; w2r[k] = sW2[h];
            ur0[k] = sU[h]; ur1[k] = sU[256 + h];
        }
        for (int j = jg; j < Ny; j += 8) {
            const float4* wr4 = (const float4*)(w + (((size_t)(b * Ny + j)) << 8) + (hh << 3));
            float4 wa = wr4[0], wb = wr4[1];
            float dv0 = sDis[j], dv1 = sDis[128 + j];
            float wv8[8] = {wa.x, wa.y, wa.z, wa.w, wb.x, wb.y, wb.z, wb.w};
            float a0 = 0.f, a1 = 0.f;
            #pragma unroll
            for (int k = 0; k < 8; ++k) {
                float h0 = fmaf(cr[k], dv0, ur0[k] + wv8[k]);
                float h1 = fmaf(cr[k], dv1, ur1[k] + wv8[k]);
                a0 = fmaf(w2r[k], fmaxf(h0, 0.f), a0);
                a1 = fmaf(w2r[k], fmaxf(h1, 0.f), a1);
            }
            #pragma unroll
            for (int m = 16; m; m >>= 1) {
                a0 += __shfl_xor(a0, m);
                a1 += __shfl_xor(a1, m);
            }
            if (hh == 0) { sS[j] = a0; sS[128 + j] = a1; }
        }
    }
    __syncthreads();

    // phase 4: softmax — one wave per i-row
    if (tid < 128) {
        const int il = tid >> 6, lane = tid & 63;
        float* row = sS + (il << 7);
        float m = -1e30f;
        for (int j = lane; j < Ny; j += 64) m = fmaxf(m, row[j]);
        #pragma unroll
        for (int msk = 32; msk; msk >>= 1) m = fmaxf(m, __shfl_xor(m, msk));
        float s = 0.f;
        for (int j = lane; j < Ny; j += 64) { float ev = __expf(row[j] - m); row[j] = ev; s += ev; }
        #pragma unroll
        for (int msk = 32; msk; msk >>= 1) s += __shfl_xor(s, msk);
        float inv = 1.0f / s;
        for (int j = lane; j < Ny; j += 64) row[j] *= inv;
    }
    __syncthreads();

    // edge output (stage 7 only)
    if (ep) {
        for (int k = tid; k < (TI * 128) && (k >> 7) < TI; k += 256) {
            int il = k >> 7, j = k & 127;
            if (j < Ny) ep[((size_t)(b * Nx + i0 + il)) * Ny + j] = sS[(il << 7) + j];
        }
    }

    // phase 5: agg = e @ yv ; thread (jg, dd), LDS-tree reduce
    {
        const int jg = tid >> 5, dd = tid & 31;
        float p0 = 0.f, p1 = 0.f;
        for (int j = jg; j < Ny; j += 8) {
            float v = yv[(((size_t)(b * Ny + j)) << 5) + dd];
            p0 = fmaf(sS[j], v, p0);
            p1 = fmaf(sS[128 + j], v, p1);
        }
        sRed[(jg << 6) + dd] = p0;
        sRed[(jg << 6) + 32 + dd] = p1;
    }
    __syncthreads();
    if (tid < 64) {
        float a = 0.f;
        #pragma unroll
        for (int jg = 0; jg < 8; ++jg) a += sRed[(jg << 6) + tid];
        sAgg[tid] = a;
    }
    __syncthreads();

    // phase 7: node-MLP hidden
    {
        const float4* w14 = (const float4*)(Wn1 + (tid << 6));
        float a0 = bn1[tid], a1 = a0;
        #pragma unroll
        for (int k = 0; k < 8; ++k) {
            float4 wa = w14[k];
            a0 += dot4(wa, ((const float4*)sX)[k]);
            a1 += dot4(wa, ((const float4*)(sX + 32))[k]);
        }
        #pragma unroll
        for (int k = 0; k < 8; ++k) {
            float4 wb = w14[8 + k];
            a0 += dot4(wb, ((const float4*)sAgg)[k]);
            a1 += dot4(wb, ((const float4*)(sAgg + 32))[k]);
        }
        sT[tid] = fmaxf(a0, 0.f);
        sT[256 + tid] = fmaxf(a1, 0.f);
    }
    __syncthreads();

    // phase 8: out = x + T @ Wn2^T + bn2
    {
        const int hg = tid >> 5, dd = tid & 31;
        const float4* w24 = (const float4*)(Wn2 + (dd << 8) + (hg << 5));
        float p0 = 0.f, p1 = 0.f;
        #pragma unroll
        for (int k = 0; k < 8; ++k) {
            float4 wv4 = w24[k];
            p0 += dot4(wv4, ((const float4*)(sT + (hg << 5)))[k]);
            p1 += dot4(wv4, ((const float4*)(sT + 256 + (hg << 5)))[k]);
        }
        sRed[(hg << 6) + dd] = p0;
        sRed[(hg << 6) + 32 + dd] = p1;
    }
    __syncthreads();
    if (tid < 64) {
        int il = tid >> 5, dd = tid & 31;
        float a = bn2[dd] + sX[tid];
        #pragma unroll
        for (int hg = 0; hg < 8; ++hg) a += sRed[(hg << 6) + tid];
        outp[((size_t)(b * Nx + i0 + il)) * 32 + dd] = a;
        sOut[tid] = a;
    }

    // fused pre_y for the next stage (stage-6 blocks only)
    if (wPre) {
        __syncthreads();
        if (tid < 128) {
            int half = tid >> 6, t = tid & 63;
            int il = t >> 5, dd = t & 31;
            const float4* wm4 = (const float4*)((half ? Wv : Wk) + (dd << 5));
            const float4* orow = (const float4*)(sOut + (il << 5));
            float a = half ? bv[dd] : bk[dd];
            #pragma unroll
            for (int k = 0; k < 8; ++k) a += dot4(wm4[k], orow[k]);
            if (half) yvPre[(((size_t)(b * Nx + i0 + il)) << 5) + dd] = a;
            else sYK[il * 33 + dd] = a;
        }
        __syncthreads();
        {
            const float* w1 = We1 + tid * 65 + 32;
            float a0 = 0.f, a1 = 0.f;
            #pragma unroll
            for (int e = 0; e < 32; ++e) {
                float we = w1[e];
                a0 = fmaf(we, sYK[e], a0);
                a1 = fmaf(we, sYK[33 + e], a1);
            }
            wPre[(((size_t)(b * Nx + i0)) << 8) + tid] = a0;
            wPre[(((size_t)(b * Nx + i0 + 1)) << 8) + tid] = a1;
        }
    }
}

// ---------------------------------------------------------------------------
extern "C" void kernel_launch(void* const* d_in, const int* in_sizes, int n_in,
                              void* d_out, int out_size, void* d_ws, size_t ws_size,
                              hipStream_t stream) {
    const float* robot          = (const float*)d_in[0];
    const float* frontier       = (const float*)d_in[1];
    const float* rh             = (const float*)d_in[2];
    const float* fh             = (const float*)d_in[3];
    const float* robot_frontier = (const float*)d_in[4];
    const float* robot_past     = (const float*)d_in[5];
    const float* frontier_past  = (const float*)d_in[6];
    const float* Wq  = (const float*)d_in[7];  const float* bq  = (const float*)d_in[8];
    const float* Wk  = (const float*)d_in[9];  const float* bk  = (const float*)d_in[10];
    const float* Wv  = (const float*)d_in[11]; const float* bv  = (const float*)d_in[12];
    const float* Wn1 = (const float*)d_in[13]; const float* bn1 = (const float*)d_in[14];
    const float* Wn2 = (const float*)d_in[15]; const float* bn2 = (const float*)d_in[16];
    const float* We1 = (const float*)d_in[17]; const float* be1 = (const float*)d_in[18];
    const float* We2 = (const float*)d_in[19];

    float* out = (float*)d_out;
    float* out_robot    = out;            // 32*32*32   = 32768
    float* out_frontier = out + 32768;    // 32*128*32  = 131072
    float* out_rh       = out + 163840;   // 32*64*32   = 65536
    float* out_fh       = out + 229376;   // 32*64*32   = 65536
    float* out_edge     = out + 294912;   // 32*32*128  = 131072

    float* W = (float*)d_ws;
    float* robot1 = W;                 // 32768
    float* robot2 = W + 32768;         // 32768
    float* nf     = W + 65536;         // 131072
    float* w5     = W + 196608;        // 32*64*256  = 524288
    float* yv5    = W + 720896;        // 65536
    float* w6     = W + 786432;        // 524288
    float* yv6    = W + 1310720;       // 65536
    float* w7     = W + 1376256;       // 32*128*256 = 1048576
    float* yv7    = W + 2424832;       // 131072

    // 1. four intra-attentions + fused pre_y for stages 5/6
    intra_kernel<<<288, 256, 0, stream>>>(robot, frontier, rh, fh,
        Wq, bq, Wk, bk, Wv, bv, Wn1, bn1, Wn2, bn2, We1,
        robot1, out_frontier, out_rh, out_fh, w5, yv5, w6, yv6);

    // 2. inter stage 5 (robot1 x rh1) + stage 6 (frontier1 x fh1, fused pre_y
    //    for stage 7 from the nf rows)
    inter_main_kernel<<<2560, 256, 0, stream>>>(
        robot1, NRr, w5, yv5, NHh, robot_past, robot2,
        (float*)nullptr, (float*)nullptr, (float*)nullptr, BATCH * (NRr / TI),
        out_frontier, NFf, w6, yv6, NFHh, frontier_past, nf,
        (float*)nullptr, w7, yv7,
        Wq, bq, Wk, bk, Wv, bv, We1, be1, We2, Wn1, bn1, Wn2, bn2);

    // 3. inter stage 7 (robot2 x new_frontier) -> final robot + edge
    inter_main_kernel<<<512, 256, 0, stream>>>(
        robot2, NRr, w7, yv7, NFf, robot_frontier, out_robot, out_edge,
        (float*)nullptr, (float*)nullptr, BATCH * (NRr / TI),
        robot2, NRr, w7, yv7, NFf, robot_frontier, out_robot, out_edge,
        (float*)nullptr, (float*)nullptr,
        Wq, bq, Wk, bk, Wv, bv, We1, be1, We2, Wn1, bn1, Wn2, bn2);
}

// Round 4
// 234.923 us; speedup vs baseline: 1.6242x; 1.6242x over previous
//
#include <hip/hip_runtime.h>

#define BATCH 32
#define NRr 32
#define NFf 128
#define NHh 64
#define NFHh 64
#define TI 2

__device__ __forceinline__ float dot4(float4 a, float4 b) {
    return fmaf(a.x, b.x, fmaf(a.y, b.y, fmaf(a.z, b.z, a.w * b.w)));
}

// ---------------------------------------------------------------------------
// intra (R2 version): x -> x + nmlp([x, softmax(qk^T) v]) for all 4 tensors.
// grid = 288 blocks: robot [0,32), frontier [32,160), rh [160,224), fh [224,288)
// NOTE: no pre_y fusion here — R3 showed it pushes VGPR to 256 + spills.
// ---------------------------------------------------------------------------
__global__ __launch_bounds__(256) void intra_kernel(
    const float* __restrict__ robot, const float* __restrict__ frontier,
    const float* __restrict__ rhist, const float* __restrict__ fhist,
    const float* __restrict__ Wq, const float* __restrict__ bq,
    const float* __restrict__ Wk, const float* __restrict__ bk,
    const float* __restrict__ Wv, const float* __restrict__ bv,
    const float* __restrict__ Wn1, const float* __restrict__ bn1,
    const float* __restrict__ Wn2, const float* __restrict__ bn2,
    float* __restrict__ o_robot, float* __restrict__ o_frontier,
    float* __restrict__ o_rh, float* __restrict__ o_fh)
{
    __shared__ __align__(16) float sXc[1024];    // chunk rows of x (32x32)
    __shared__ __align__(16) float sQ[1024];     // chunk q (32x32)
    __shared__ __align__(16) float sAgg[1024];   // chunk agg (32x32)
    __shared__ __align__(16) float sS[4096];     // scores chunk (32 x N)
    __shared__ __align__(16) float sKT[4128];    // K^T [32][129] (pad kills bank conflicts)
    __shared__ __align__(16) float sVT[8192];    // V (N*32), later overlaid by T (32x256)

    const int blk = blockIdx.x, tid = threadIdx.x;
    const float* xin; float* xout; int N, lgN, b, chunk;
    if (blk < 32)       { xin=robot;    xout=o_robot;    N=32;  lgN=5; b=blk;          chunk=0; }
    else if (blk < 160) { xin=frontier; xout=o_frontier; N=128; lgN=7; b=(blk-32)>>2;  chunk=(blk-32)&3; }
    else if (blk < 224) { xin=rhist;    xout=o_rh;       N=64;  lgN=6; b=(blk-160)>>1; chunk=(blk-160)&1; }
    else                { xin=fhist;    xout=o_fh;       N=64;  lgN=6; b=(blk-224)>>1; chunk=(blk-224)&1; }

    const float* xb = xin + (size_t)b * N * 32;
    const int r0 = chunk << 5;
    const int d = tid & 31;

    // load chunk rows of x into LDS
    {
        int idx = tid;
        #pragma unroll
        for (int it = 0; it < 4; ++it, idx += 256)
            sXc[idx] = xb[(r0 << 5) + idx];
    }

    // K^T, V for all N rows; weight rows hoisted to registers
    {
        const float4* wk4 = (const float4*)(Wk + (d << 5));
        const float4* wv4 = (const float4*)(Wv + (d << 5));
        float4 wk[8], wv[8];
        #pragma unroll
        for (int k = 0; k < 8; ++k) { wk[k] = wk4[k]; wv[k] = wv4[k]; }
        const float bkd = bk[d], bvd = bv[d];
        for (int idx = tid; idx < (N << 5); idx += 256) {
            int j = idx >> 5;
            const float4* xr = (const float4*)(xb + (j << 5));
            float aK = bkd, aV = bvd;
            #pragma unroll
            for (int k = 0; k < 8; ++k) {
                float4 xv = xr[k];
                aK += dot4(wk[k], xv);
                aV += dot4(wv[k], xv);
            }
            sKT[d * 129 + j] = aK;
            sVT[(j << 5) + d] = aV;
        }
    }
    __syncthreads();

    // Q for chunk rows (weight row hoisted)
    {
        const float4* wq4 = (const float4*)(Wq + (d << 5));
        float4 wq[8];
        #pragma unroll
        for (int k = 0; k < 8; ++k) wq[k] = wq4[k];
        const float bqd = bq[d];
        int idx = tid;
        #pragma unroll
        for (int it = 0; it < 4; ++it, idx += 256) {
            int r = idx >> 5;
            const float4* xr = (const float4*)(sXc + (r << 5));
            float a = bqd;
            #pragma unroll
            for (int k = 0; k < 8; ++k) a += dot4(wq[k], xr[k]);
            sQ[idx] = a;
        }
    }
    __syncthreads();

    // scores chunk: [32, N]; K^T reads conflict-free, Q reads broadcast
    for (int idx = tid; idx < (N << 5); idx += 256) {
        int r = idx >> lgN, j = idx & (N - 1);
        const float* qr = sQ + (r << 5);
        float a = 0.f;
        #pragma unroll
        for (int e = 0; e < 32; ++e) a = fmaf(qr[e], sKT[e * 129 + j], a);
        sS[idx] = a;
    }
    __syncthreads();

    // softmax per row: 32 rows x 8 lanes
    {
        int r = tid >> 3, l = tid & 7;
        float* row = sS + (r << lgN);
        float m = -1e30f;
        for (int j = l; j < N; j += 8) m = fmaxf(m, row[j]);
        m = fmaxf(m, __shfl_xor(m, 4));
        m = fmaxf(m, __shfl_xor(m, 2));
        m = fmaxf(m, __shfl_xor(m, 1));
        float s = 0.f;
        for (int j = l; j < N; j += 8) { float ev = __expf(row[j] - m); row[j] = ev; s += ev; }
        s += __shfl_xor(s, 4); s += __shfl_xor(s, 2); s += __shfl_xor(s, 1);
        float inv = 1.0f / s;
        for (int j = l; j < N; j += 8) row[j] *= inv;
    }
    __syncthreads();

    // agg = e @ V
    {
        int idx = tid;
        #pragma unroll
        for (int it = 0; it < 4; ++it, idx += 256) {
            int r = idx >> 5;
            const float* er = sS + (r << lgN);
            float a = 0.f;
            for (int j = 0; j < N; ++j) a = fmaf(er[j], sVT[(j << 5) + d], a);
            sAgg[idx] = a;
        }
    }
    __syncthreads();

    // T = relu([x, agg] @ Wn1^T + bn1): thread h = tid, loop over 32 rows
    float* sT = sVT;
    {
        const float4* w14 = (const float4*)(Wn1 + (tid << 6));
        float4 w1r[16];
        #pragma unroll
        for (int k = 0; k < 16; ++k) w1r[k] = w14[k];
        const float b1 = bn1[tid];
        for (int r = 0; r < 32; ++r) {
            const float4* xr = (const float4*)(sXc + (r << 5));
            const float4* ar = (const float4*)(sAgg + (r << 5));
            float a = b1;
            #pragma unroll
            for (int k = 0; k < 8; ++k) a += dot4(w1r[k], xr[k]);
            #pragma unroll
            for (int k = 0; k < 8; ++k) a += dot4(w1r[8 + k], ar[k]);
            sT[(r << 8) + tid] = fmaxf(a, 0.f);
        }
    }
    __syncthreads();

    // out = x + T @ Wn2^T + bn2: thread (rg=tid>>5, d), 4 rows each, h chunked
    {
        const int rg = tid >> 5;
        float acc[4] = {0.f, 0.f, 0.f, 0.f};
        #pragma unroll
        for (int hc = 0; hc < 4; ++hc) {
            const float4* w24 = (const float4*)(Wn2 + (d << 8) + (hc << 6));
            float4 w2r[16];
            #pragma unroll
            for (int k = 0; k < 16; ++k) w2r[k] = w24[k];
            #pragma unroll
            for (int p = 0; p < 4; ++p) {
                int r = rg + (p << 3);
                const float4* tr = (const float4*)(sT + (r << 8) + (hc << 6));
                float a = 0.f;
                #pragma unroll
                for (int k = 0; k < 16; ++k) a += dot4(w2r[k], tr[k]);
                acc[p] += a;
            }
        }
        const float b2 = bn2[d];
        #pragma unroll
        for (int p = 0; p < 4; ++p) {
            int r = rg + (p << 3);
            xout[((size_t)b * N << 5) + ((r0 + r) << 5) + d] = sXc[(r << 5) + d] + b2 + acc[p];
        }
    }
}

// ---------------------------------------------------------------------------
// pre_y v2: block = 8 j's of the y-tensor: yk, yv, w_j[h] = We1[h,32:64].yk_j
// ---------------------------------------------------------------------------
__global__ __launch_bounds__(256) void pre_y_kernel(
    const float* __restrict__ yA, int NyA, float* __restrict__ wOutA, float* __restrict__ yvOutA, int nBlkA,
    const float* __restrict__ yB, int NyB, float* __restrict__ wOutB, float* __restrict__ yvOutB,
    const float* __restrict__ Wk, const float* __restrict__ bk,
    const float* __restrict__ Wv, const float* __restrict__ bv,
    const float* __restrict__ We1)
{
    __shared__ __align__(16) float sY[256], sK[256];
    const int blk = blockIdx.x, tid = threadIdx.x;
    const float* y; int Ny; float* wOut; float* yvOut; int idx;
    if (blk < nBlkA) { y=yA; Ny=NyA; wOut=wOutA; yvOut=yvOutA; idx=blk; }
    else             { y=yB; Ny=NyB; wOut=wOutB; yvOut=yvOutB; idx=blk-nBlkA; }
    const int chunks = Ny >> 3;
    const int b = idx / chunks, j0 = (idx - b * chunks) << 3;

    // load 8 y rows (256 floats, contiguous)
    sY[tid] = y[((size_t)(b * Ny + j0)) * 32 + tid];
    __syncthreads();

    // yk -> LDS, yv -> global
    {
        int jl = tid >> 5, dd = tid & 31;
        const float4* wk4 = (const float4*)(Wk + (dd << 5));
        const float4* wv4 = (const float4*)(Wv + (dd << 5));
        const float4* yr = (const float4*)(sY + (jl << 5));
        float aK = bk[dd], aV = bv[dd];
        #pragma unroll
        for (int k = 0; k < 8; ++k) {
            float4 yv4 = yr[k];
            aK += dot4(wk4[k], yv4);
            aV += dot4(wv4[k], yv4);
        }
        sK[(jl << 5) + dd] = aK;
        yvOut[((size_t)(b * Ny + j0 + jl)) * 32 + dd] = aV;
    }
    __syncthreads();

    // w rows: thread h = tid computes 8 j's
    {
        const float* w1 = We1 + tid * 65 + 32;
        float acc[8] = {0,0,0,0,0,0,0,0};
        #pragma unroll
        for (int e = 0; e < 32; ++e) {
            float we = w1[e];
            #pragma unroll
            for (int jl = 0; jl < 8; ++jl)
                acc[jl] = fmaf(we, sK[(jl << 5) + e], acc[jl]);
        }
        #pragma unroll
        for (int jl = 0; jl < 8; ++jl)
            wOut[((size_t)(b * Ny + j0 + jl)) * 256 + tid] = acc[jl];
    }
}

// ---------------------------------------------------------------------------
// inter v3 (no pre-tail): block = (b, TI=2 i's). Phase-3 j-loop is
// register-resident (u/c/w2 hoisted per lane) with float4 w-row loads.
// ---------------------------------------------------------------------------
__global__ __launch_bounds__(256) void inter_main_kernel(
    const float* __restrict__ xA, int NxA, const float* __restrict__ wA, const float* __restrict__ yvA,
    int NyA, const float* __restrict__ disA, float* __restrict__ outA, float* __restrict__ eA, int nBlkA,
    const float* __restrict__ xB, int NxB, const float* __restrict__ wB, const float* __restrict__ yvB,
    int NyB, const float* __restrict__ disB, float* __restrict__ outB, float* __restrict__ eB,
    const float* __restrict__ Wq, const float* __restrict__ bq,
    const float* __restrict__ We1, const float* __restrict__ be1,
    const float* __restrict__ We2,
    const float* __restrict__ Wn1, const float* __restrict__ bn1,
    const float* __restrict__ Wn2, const float* __restrict__ bn2)
{
    __shared__ __align__(16) float sX[64], sQ[64], sAgg[64];
    __shared__ __align__(16) float sDis[256];     // [TI][128]
    __shared__ __align__(16) float sU[512];       // [TI][256]
    __shared__ __align__(16) float sC[256], sW2[256];
    __shared__ __align__(16) float sS[256];       // [TI][128]
    __shared__ __align__(16) float sRed[512];     // [8][TI*32]
    __shared__ __align__(16) float sT[512];       // [TI][256]

    const int blk = blockIdx.x, tid = threadIdx.x;
    const float* x; int Nx; const float* w; const float* yv; int Ny;
    const float* dis; float* outp; float* ep; int idx;
    if (blk < nBlkA) { x=xA; Nx=NxA; w=wA; yv=yvA; Ny=NyA; dis=disA; outp=outA; ep=eA; idx=blk; }
    else             { x=xB; Nx=NxB; w=wB; yv=yvB; Ny=NyB; dis=disB; outp=outB; ep=eB; idx=blk-nBlkA; }
    const int tiles = Nx >> 1;
    const int b = idx / tiles, i0 = (idx - b * tiles) << 1;
    const float* xrow = x + ((size_t)(b * Nx + i0)) * 32;

    // phase 0: stage x tile + dis tile (float4)
    if (tid < 64) sX[tid] = xrow[tid];
    {
        int per = Ny >> 2;                 // float4s per row (16 or 32)
        if (tid < (per << 1)) {
            int il = (tid >= per) ? 1 : 0, jq = tid - il * per;
            ((float4*)sDis)[(il << 5) + jq] =
                ((const float4*)(dis + ((size_t)(b * Nx + i0 + il)) * Ny))[jq];
        }
    }
    __syncthreads();

    // phase 1: Q for TI rows
    if (tid < 64) {
        int il = tid >> 5, dd = tid & 31;
        const float4* wq4 = (const float4*)(Wq + (dd << 5));
        const float4* xr = (const float4*)(sX + (il << 5));
        float a = bq[dd];
        #pragma unroll
        for (int k = 0; k < 8; ++k) a += dot4(wq4[k], xr[k]);
        sQ[tid] = a;
    }
    __syncthreads();

    // phase 2: u, c, w2
    {
        const float* w1 = We1 + tid * 65;
        float a0 = be1[tid], a1 = a0;
        #pragma unroll
        for (int e = 0; e < 32; ++e) {
            float we = w1[e];
            a0 = fmaf(we, sQ[e], a0);
            a1 = fmaf(we, sQ[32 + e], a1);
        }
        sU[tid] = a0; sU[256 + tid] = a1;
        sC[tid] = w1[64];
        sW2[tid] = We2[tid];
    }
    __syncthreads();

    // phase 3: scores; lane hh owns h = hh*8..hh*8+7, all state in registers
    {
        const int jg = tid >> 5, hh = tid & 31;
        float ur0[8], ur1[8], cr[8], w2r[8];
        #pragma unroll
        for (int k = 0; k < 8; ++k) {
            int h = (hh << 3) + k;
            cr[k] = sC[h]; w2r[k] = sW2[h];
            ur0[k] = sU[h]; ur1[k] = sU[256 + h];
        }
        for (int j = jg; j < Ny; j += 8) {
            const float4* wr4 = (const float4*)(w + (((size_t)(b * Ny + j)) << 8) + (hh << 3));
            float4 wa = wr4[0], wb = wr4[1];
            float dv0 = sDis[j], dv1 = sDis[128 + j];
            float wv8[8] = {wa.x, wa.y, wa.z, wa.w, wb.x, wb.y, wb.z, wb.w};
            float a0 = 0.f, a1 = 0.f;
            #pragma unroll
            for (int k = 0; k < 8; ++k) {
                float h0 = fmaf(cr[k], dv0, ur0[k] + wv8[k]);
                float h1 = fmaf(cr[k], dv1, ur1[k] + wv8[k]);
                a0 = fmaf(w2r[k], fmaxf(h0, 0.f), a0);
                a1 = fmaf(w2r[k], fmaxf(h1, 0.f), a1);
            }
            #pragma unroll
            for (int m = 16; m; m >>= 1) {
                a0 += __shfl_xor(a0, m);
                a1 += __shfl_xor(a1, m);
            }
            if (hh == 0) { sS[j] = a0; sS[128 + j] = a1; }
        }
    }
    __syncthreads();

    // phase 4: softmax — one wave per i-row
    if (tid < 128) {
        const int il = tid >> 6, lane = tid & 63;
        float* row = sS + (il << 7);
        float m = -1e30f;
        for (int j = lane; j < Ny; j += 64) m = fmaxf(m, row[j]);
        #pragma unroll
        for (int msk = 32; msk; msk >>= 1) m = fmaxf(m, __shfl_xor(m, msk));
        float s = 0.f;
        for (int j = lane; j < Ny; j += 64) { float ev = __expf(row[j] - m); row[j] = ev; s += ev; }
        #pragma unroll
        for (int msk = 32; msk; msk >>= 1) s += __shfl_xor(s, msk);
        float inv = 1.0f / s;
        for (int j = lane; j < Ny; j += 64) row[j] *= inv;
    }
    __syncthreads();

    // edge output (stage 7 only)
    if (ep) {
        for (int k = tid; k < TI * 128; k += 256) {
            int il = k >> 7, j = k & 127;
            if (j < Ny) ep[((size_t)(b * Nx + i0 + il)) * Ny + j] = sS[(il << 7) + j];
        }
    }

    // phase 5: agg = e @ yv ; thread (jg, dd), LDS-tree reduce
    {
        const int jg = tid >> 5, dd = tid & 31;
        float p0 = 0.f, p1 = 0.f;
        for (int j = jg; j < Ny; j += 8) {
            float v = yv[(((size_t)(b * Ny + j)) << 5) + dd];
            p0 = fmaf(sS[j], v, p0);
            p1 = fmaf(sS[128 + j], v, p1);
        }
        sRed[(jg << 6) + dd] = p0;
        sRed[(jg << 6) + 32 + dd] = p1;
    }
    __syncthreads();
    if (tid < 64) {
        float a = 0.f;
        #pragma unroll
        for (int jg = 0; jg < 8; ++jg) a += sRed[(jg << 6) + tid];
        sAgg[tid] = a;
    }
    __syncthreads();

    // phase 7: node-MLP hidden
    {
        const float4* w14 = (const float4*)(Wn1 + (tid << 6));
        float a0 = bn1[tid], a1 = a0;
        #pragma unroll
        for (int k = 0; k < 8; ++k) {
            float4 wa = w14[k];
            a0 += dot4(wa, ((const float4*)sX)[k]);
            a1 += dot4(wa, ((const float4*)(sX + 32))[k]);
        }
        #pragma unroll
        for (int k = 0; k < 8; ++k) {
            float4 wb = w14[8 + k];
            a0 += dot4(wb, ((const float4*)sAgg)[k]);
            a1 += dot4(wb, ((const float4*)(sAgg + 32))[k]);
        }
        sT[tid] = fmaxf(a0, 0.f);
        sT[256 + tid] = fmaxf(a1, 0.f);
    }
    __syncthreads();

    // phase 8: out = x + T @ Wn2^T + bn2
    {
        const int hg = tid >> 5, dd = tid & 31;
        const float4* w24 = (const float4*)(Wn2 + (dd << 8) + (hg << 5));
        float p0 = 0.f, p1 = 0.f;
        #pragma unroll
        for (int k = 0; k < 8; ++k) {
            float4 wv4 = w24[k];
            p0 += dot4(wv4, ((const float4*)(sT + (hg << 5)))[k]);
            p1 += dot4(wv4, ((const float4*)(sT + 256 + (hg << 5)))[k]);
        }
        sRed[(hg << 6) + dd] = p0;
        sRed[(hg << 6) + 32 + dd] = p1;
    }
    __syncthreads();
    if (tid < 64) {
        int il = tid >> 5, dd = tid & 31;
        float a = bn2[dd] + sX[tid];
        #pragma unroll
        for (int hg = 0; hg < 8; ++hg) a += sRed[(hg << 6) + tid];
        outp[((size_t)(b * Nx + i0 + il)) * 32 + dd] = a;
    }
}

// ---------------------------------------------------------------------------
extern "C" void kernel_launch(void* const* d_in, const int* in_sizes, int n_in,
                              void* d_out, int out_size, void* d_ws, size_t ws_size,
                              hipStream_t stream) {
    const float* robot          = (const float*)d_in[0];
    const float* frontier       = (const float*)d_in[1];
    const float* rh             = (const float*)d_in[2];
    const float* fh             = (const float*)d_in[3];
    const float* robot_frontier = (const float*)d_in[4];
    const float* robot_past     = (const float*)d_in[5];
    const float* frontier_past  = (const float*)d_in[6];
    const float* Wq  = (const float*)d_in[7];  const float* bq  = (const float*)d_in[8];
    const float* Wk  = (const float*)d_in[9];  const float* bk  = (const float*)d_in[10];
    const float* Wv  = (const float*)d_in[11]; const float* bv  = (const float*)d_in[12];
    const float* Wn1 = (const float*)d_in[13]; const float* bn1 = (const float*)d_in[14];
    const float* Wn2 = (const float*)d_in[15]; const float* bn2 = (const float*)d_in[16];
    const float* We1 = (const float*)d_in[17]; const float* be1 = (const float*)d_in[18];
    const float* We2 = (const float*)d_in[19];

    float* out = (float*)d_out;
    float* out_robot    = out;            // 32*32*32   = 32768
    float* out_frontier = out + 32768;    // 32*128*32  = 131072
    float* out_rh       = out + 163840;   // 32*64*32   = 65536
    float* out_fh       = out + 229376;   // 32*64*32   = 65536
    float* out_edge     = out + 294912;   // 32*32*128  = 131072

    float* W = (float*)d_ws;
    float* robot1 = W;                 // 32768
    float* robot2 = W + 32768;         // 32768
    float* nf     = W + 65536;         // 131072
    float* w5     = W + 196608;        // 32*64*256  = 524288
    float* yv5    = W + 720896;        // 65536
    float* w6     = W + 786432;        // 524288
    float* yv6    = W + 1310720;       // 65536
    float* w7     = W + 1376256;       // 32*128*256 = 1048576
    float* yv7    = W + 2424832;       // 131072

    // 1. all four intra-attentions
    intra_kernel<<<288, 256, 0, stream>>>(robot, frontier, rh, fh,
        Wq, bq, Wk, bk, Wv, bv, Wn1, bn1, Wn2, bn2,
        robot1, out_frontier, out_rh, out_fh);

    // 2. y-side precompute for inter stage 5 (y=rh1) and stage 6 (y=fh1)
    pre_y_kernel<<<512, 256, 0, stream>>>(
        out_rh, NHh, w5, yv5, BATCH * NHh / 8,
        out_fh, NFHh, w6, yv6,
        Wk, bk, Wv, bv, We1);

    // 3. inter stage 5 (robot1 x rh1) and stage 6 (frontier1 x fh1)
    inter_main_kernel<<<2560, 256, 0, stream>>>(
        robot1, NRr, w5, yv5, NHh, robot_past, robot2, (float*)nullptr, BATCH * (NRr / TI),
        out_frontier, NFf, w6, yv6, NFHh, frontier_past, nf, (float*)nullptr,
        Wq, bq, We1, be1, We2, Wn1, bn1, Wn2, bn2);

    // 4. y-side precompute for inter stage 7 (y = new_frontier)
    pre_y_kernel<<<512, 256, 0, stream>>>(
        nf, NFf, w7, yv7, BATCH * NFf / 8,
        nf, NFf, w7, yv7,   // B unused (grid == nBlkA)
        Wk, bk, Wv, bv, We1);

    // 5. inter stage 7 (robot2 x new_frontier) -> final robot + edge
    inter_main_kernel<<<512, 256, 0, stream>>>(
        robot2, NRr, w7, yv7, NFf, robot_frontier, out_robot, out_edge, BATCH * (NRr / TI),
        robot2, NRr, w7, yv7, NFf, robot_frontier, out_robot, out_edge,  // B unused
        Wq, bq, We1, be1, We2, Wn1, bn1, Wn2, bn2);
}